// Round 3
// baseline (387.937 us; speedup 1.0000x reference)
//
#include <hip/hip_runtime.h>

typedef short bf16x8 __attribute__((ext_vector_type(8)));
typedef float f32x4 __attribute__((ext_vector_type(4)));

__device__ __forceinline__ unsigned short f2bf(float f) {
  unsigned int u = __float_as_uint(f);
  u += 0x7fffu + ((u >> 16) & 1u);
  return (unsigned short)(u >> 16);
}
__device__ __forceinline__ float bf2f(unsigned short h) {
  return __uint_as_float(((unsigned int)h) << 16);
}
__device__ __forceinline__ float lrelu(float a) { return a >= 0.f ? a : 0.2f * a; }

// ---------------- zero workspace region ----------------
__global__ void zero_kernel(int* __restrict__ p, int n) {
  int i = blockIdx.x * blockDim.x + threadIdx.x;
  int stride = gridDim.x * blockDim.x;
  for (; i < n; i += stride) p[i] = 0;
}

// ---------------- GEMM: xl[n,c] = sum_k x[n,k] * W[c,k]  (f32 in, bf16 out) ----------------
__global__ __launch_bounds__(256) void gemm_kernel(
    const float* __restrict__ x, const float* __restrict__ w,
    unsigned short* __restrict__ xl, int n) {
  __shared__ __align__(16) unsigned short xs[64 * 128];   // 16 KB, swizzled
  __shared__ __align__(16) unsigned short wl[128 * 128];  // 32 KB, swizzled
  const int t = threadIdx.x;
  const int r0 = blockIdx.x * 64;
  // stage W (128x128 f32 -> bf16)
#pragma unroll
  for (int i = 0; i < 16; ++i) {
    int f4 = t + i * 256;
    int row = f4 >> 5;
    int kk = (f4 & 31) << 2;
    float4 v = *(const float4*)(w + row * 128 + kk);
    ushort4 b;
    b.x = f2bf(v.x); b.y = f2bf(v.y); b.z = f2bf(v.z); b.w = f2bf(v.w);
    int boff = (kk << 1) ^ ((row & 7) << 4);
    *(ushort4*)((char*)wl + row * 256 + boff) = b;
  }
  // stage x tile (64 rows)
#pragma unroll
  for (int i = 0; i < 8; ++i) {
    int f4 = t + i * 256;
    int row = f4 >> 5;
    int kk = (f4 & 31) << 2;
    int gr = r0 + row;
    float4 v;
    if (gr < n) v = *(const float4*)(x + gr * 128 + kk);
    else { v.x = 0.f; v.y = 0.f; v.z = 0.f; v.w = 0.f; }
    ushort4 b;
    b.x = f2bf(v.x); b.y = f2bf(v.y); b.z = f2bf(v.z); b.w = f2bf(v.w);
    int boff = (kk << 1) ^ ((row & 7) << 4);
    *(ushort4*)((char*)xs + row * 256 + boff) = b;
  }
  __syncthreads();
  const int wid = t >> 6, lane = t & 63;
  const int m16 = lane & 15, kg = lane >> 4;
  const int arow = wid * 16 + m16;
  const f32x4 vzero = {0.f, 0.f, 0.f, 0.f};
  f32x4 acc[8];
#pragma unroll
  for (int i = 0; i < 8; ++i) acc[i] = vzero;
#pragma unroll
  for (int s = 0; s < 4; ++s) {
    int kb = s * 64 + kg * 16;
    bf16x8 a = *(const bf16x8*)((const char*)xs + arow * 256 + (kb ^ ((arow & 7) << 4)));
#pragma unroll
    for (int cf = 0; cf < 8; ++cf) {
      int wrow = cf * 16 + m16;
      bf16x8 b = *(const bf16x8*)((const char*)wl + wrow * 256 + (kb ^ ((wrow & 7) << 4)));
      acc[cf] = __builtin_amdgcn_mfma_f32_16x16x32_bf16(a, b, acc[cf], 0, 0, 0);
    }
  }
  // C/D layout: col = cf*16 + (lane&15), row = wid*16 + (lane>>4)*4 + q
  const int crow0 = wid * 16 + (lane >> 4) * 4;
#pragma unroll
  for (int q = 0; q < 4; ++q) {
    int gr = r0 + crow0 + q;
    if (gr < n) {
#pragma unroll
      for (int cf = 0; cf < 8; ++cf)
        xl[gr * 128 + cf * 16 + m16] = f2bf(acc[cf][q]);
    }
  }
}

// ---------------- per-node attention scalars ai / aj ----------------
__global__ __launch_bounds__(256) void atts_kernel(
    const unsigned short* __restrict__ xl, const float* __restrict__ emb,
    const float* __restrict__ att_i, const float* __restrict__ att_j,
    const float* __restrict__ att_em_i, const float* __restrict__ att_em_j,
    float* __restrict__ ai, float* __restrict__ aj, int n) {
  int wid = threadIdx.x >> 6, lane = threadIdx.x & 63;
  int node = blockIdx.x * 4 + wid;
  if (node >= n) return;
  int c0 = lane, c1 = lane + 64;
  float x0 = bf2f(xl[node * 128 + c0]);
  float x1 = bf2f(xl[node * 128 + c1]);
  float e0 = emb[node * 128 + c0];
  float e1 = emb[node * 128 + c1];
  float si = x0 * att_i[c0] + x1 * att_i[c1] + e0 * att_em_i[c0] + e1 * att_em_i[c1];
  float sj = x0 * att_j[c0] + x1 * att_j[c1] + e0 * att_em_j[c0] + e1 * att_em_j[c1];
#pragma unroll
  for (int off = 32; off > 0; off >>= 1) {
    si += __shfl_xor(si, off);
    sj += __shfl_xor(sj, off);
  }
  if (lane == 0) { ai[node] = si; aj[node] = sj; }
}

// ---------------- CSR build ----------------
__global__ void count_kernel(const int* __restrict__ dst, int* __restrict__ cnt, int E) {
  int e = blockIdx.x * blockDim.x + threadIdx.x;
  if (e < E) atomicAdd(&cnt[dst[e]], 1);
}

__global__ __launch_bounds__(1024) void scan_kernel(
    const int* __restrict__ cnt, int* __restrict__ row_ptr, int n) {
  __shared__ int wsum[16];
  __shared__ int s_carry;
  int t = threadIdx.x, lane = t & 63, wid = t >> 6;
  if (t == 0) s_carry = 0;
  __syncthreads();
  int nIter = (n + 1023) >> 10;
  for (int it = 0; it < nIter; ++it) {
    int i = (it << 10) + t;
    int v = (i < n) ? cnt[i] : 0;
    int incl = v;
#pragma unroll
    for (int off = 1; off < 64; off <<= 1) {
      int u = __shfl_up(incl, off);
      if (lane >= off) incl += u;
    }
    if (lane == 63) wsum[wid] = incl;
    __syncthreads();
    if (wid == 0 && lane < 16) {
      int wv = wsum[lane];
      int winc = wv;
#pragma unroll
      for (int off = 1; off < 16; off <<= 1) {
        int u = __shfl_up(winc, off);
        if (lane >= off) winc += u;
      }
      wsum[lane] = winc - wv;  // exclusive wave offsets
    }
    __syncthreads();
    int excl = s_carry + wsum[wid] + incl - v;
    if (i < n) row_ptr[i] = excl;
    __syncthreads();
    if (t == 1023) s_carry = excl + v;
    __syncthreads();
  }
  if (t == 0) row_ptr[n] = s_carry;
}

__global__ void scatter_kernel(const int* __restrict__ src, const int* __restrict__ dst,
                               const int* __restrict__ rp, int* __restrict__ fill,
                               int* __restrict__ csr, int E) {
  int e = blockIdx.x * blockDim.x + threadIdx.x;
  if (e < E) {
    int d = dst[e];
    int pos = rp[d] + atomicAdd(&fill[d], 1);
    csr[pos] = src[e];
  }
}

// ---------------- fused segment-softmax + aggregation: one wave per node ----------------
__global__ __launch_bounds__(256) void agg_kernel(
    const float* __restrict__ ai, const float* __restrict__ aj,
    const unsigned short* __restrict__ xl,
    const int* __restrict__ row_ptr, const int* __restrict__ csr_src,
    const float* __restrict__ bias, float* __restrict__ out, int n) {
  int wid = threadIdx.x >> 6, lane = threadIdx.x & 63;
  int node = blockIdx.x * 4 + wid;
  if (node >= n) return;
  int beg = row_ptr[node], end = row_ptr[node + 1];
  float ain = ai[node];
  float a_self = lrelu(ain + aj[node]);
  // phase A: running max (self-loop included)
  float m = a_self;
  for (int e = beg + lane; e < end; e += 64) {
    float a = lrelu(ain + aj[csr_src[e]]);
    m = fmaxf(m, a);
  }
#pragma unroll
  for (int off = 32; off > 0; off >>= 1) m = fmaxf(m, __shfl_xor(m, off));
  // phase B: denom
  float dsum = 0.f;
  for (int e = beg + lane; e < end; e += 64) {
    float a = lrelu(ain + aj[csr_src[e]]);
    dsum += __expf(a - m);
  }
#pragma unroll
  for (int off = 32; off > 0; off >>= 1) dsum += __shfl_xor(dsum, off);
  float w_self = __expf(a_self - m);
  dsum += w_self;
  float inv = 1.f / (dsum + 1e-16f);
  // phase C: weighted feature sum; lane owns cols 2*lane, 2*lane+1
  int c0 = lane * 2;
  ushort2 u = *(const ushort2*)(xl + node * 128 + c0);
  float acc0 = w_self * bf2f(u.x);
  float acc1 = w_self * bf2f(u.y);
  for (int e = beg; e < end; ++e) {
    int s = csr_src[e];
    float a = lrelu(ain + aj[s]);
    float we = __expf(a - m);
    ushort2 v = *(const ushort2*)(xl + s * 128 + c0);
    acc0 += we * bf2f(v.x);
    acc1 += we * bf2f(v.y);
  }
  float2 o;
  o.x = acc0 * inv + bias[c0];
  o.y = acc1 * inv + bias[c0 + 1];
  *(float2*)(out + node * 128 + c0) = o;
}

// ---------------- BatchNorm stats + apply ----------------
__global__ __launch_bounds__(256) void bnstat_kernel(
    const float* __restrict__ out, float* __restrict__ sums,
    float* __restrict__ sumsq, int n) {
  int c = threadIdx.x & 127;
  int half = threadIdx.x >> 7;
  float s = 0.f, q = 0.f;
  for (int r = blockIdx.x * 2 + half; r < n; r += gridDim.x * 2) {
    float v = out[r * 128 + c];
    s += v;
    q += v * v;
  }
  atomicAdd(&sums[c], s);
  atomicAdd(&sumsq[c], q);
}

__global__ __launch_bounds__(256) void bnapply_kernel(
    float* __restrict__ out, const float* __restrict__ sums,
    const float* __restrict__ sumsq, const float* __restrict__ gamma,
    const float* __restrict__ beta, int n, float invN) {
  int total = n * 128;
  int i = blockIdx.x * blockDim.x + threadIdx.x;
  int stride = gridDim.x * blockDim.x;
  for (; i < total; i += stride) {
    int c = i & 127;
    float mu = sums[c] * invN;
    float var = sumsq[c] * invN - mu * mu;
    out[i] = (out[i] - mu) * rsqrtf(var + 1e-5f) * gamma[c] + beta[c];
  }
}

extern "C" void kernel_launch(void* const* d_in, const int* in_sizes, int n_in,
                              void* d_out, int out_size, void* d_ws, size_t ws_size,
                              hipStream_t stream) {
  (void)n_in; (void)out_size; (void)ws_size;
  const float* x = (const float*)d_in[0];
  const int* ei = (const int*)d_in[1];
  const float* emb = (const float*)d_in[2];
  const float* lin_w = (const float*)d_in[3];
  const float* att_i = (const float*)d_in[4];
  const float* att_j = (const float*)d_in[5];
  const float* att_em_i = (const float*)d_in[6];
  const float* att_em_j = (const float*)d_in[7];
  const float* bias = (const float*)d_in[8];
  const float* gamma = (const float*)d_in[9];
  const float* beta = (const float*)d_in[10];
  float* out = (float*)d_out;
  const int N = in_sizes[0] / 128;
  const int E = in_sizes[1] / 2;
  const int* src = ei;
  const int* dst = ei + E;

  auto align_up = [](size_t v) { return (v + 255) & ~(size_t)255; };
  size_t off = 0;
  size_t xl_off = off;    off = align_up(off + (size_t)N * 128 * 2);
  size_t ai_off = off;    off = align_up(off + (size_t)N * 4);
  size_t aj_off = off;    off = align_up(off + (size_t)N * 4);
  size_t rp_off = off;    off = align_up(off + (size_t)(N + 1) * 4);
  size_t csr_off = off;   off = align_up(off + (size_t)E * 4);
  size_t cnt_off = off;   off = align_up(off + (size_t)N * 4);
  size_t fill_off = off;  off = align_up(off + (size_t)N * 4);
  size_t sums_off = off;  off = align_up(off + 512);
  size_t sumsq_off = off; off = align_up(off + 512);
  size_t end_off = off;
  (void)fill_off; (void)sumsq_off;

  char* ws = (char*)d_ws;
  unsigned short* xl = (unsigned short*)(ws + xl_off);
  float* ai = (float*)(ws + ai_off);
  float* aj = (float*)(ws + aj_off);
  int* rp = (int*)(ws + rp_off);
  int* csr = (int*)(ws + csr_off);
  int* cnt = (int*)(ws + cnt_off);
  int* fill = (int*)(ws + fill_off);
  float* sums = (float*)(ws + sums_off);
  float* sumsq = (float*)(ws + sumsq_off);

  // zero cnt/fill/sums/sumsq (contiguous region)
  int zwords = (int)((end_off - cnt_off) / 4);
  hipLaunchKernelGGL(zero_kernel, dim3((zwords + 255) / 256), dim3(256), 0, stream,
                     cnt, zwords);
  hipLaunchKernelGGL(gemm_kernel, dim3((N + 63) / 64), dim3(256), 0, stream,
                     x, lin_w, xl, N);
  hipLaunchKernelGGL(atts_kernel, dim3((N + 3) / 4), dim3(256), 0, stream,
                     xl, emb, att_i, att_j, att_em_i, att_em_j, ai, aj, N);
  hipLaunchKernelGGL(count_kernel, dim3((E + 255) / 256), dim3(256), 0, stream,
                     dst, cnt, E);
  hipLaunchKernelGGL(scan_kernel, dim3(1), dim3(1024), 0, stream, cnt, rp, N);
  hipLaunchKernelGGL(scatter_kernel, dim3((E + 255) / 256), dim3(256), 0, stream,
                     src, dst, rp, fill, csr, E);
  hipLaunchKernelGGL(agg_kernel, dim3((N + 3) / 4), dim3(256), 0, stream,
                     ai, aj, xl, rp, csr, bias, out, N);
  hipLaunchKernelGGL(bnstat_kernel, dim3(256), dim3(256), 0, stream,
                     out, sums, sumsq, N);
  hipLaunchKernelGGL(bnapply_kernel, dim3(2048), dim3(256), 0, stream,
                     out, sums, sumsq, gamma, beta, N, 1.0f / (float)N);
}

// Round 4
// 290.954 us; speedup vs baseline: 1.3333x; 1.3333x over previous
//
#include <hip/hip_runtime.h>

typedef short bf16x8 __attribute__((ext_vector_type(8)));
typedef float f32x4 __attribute__((ext_vector_type(4)));

__device__ __forceinline__ unsigned short f2bf(float f) {
  unsigned int u = __float_as_uint(f);
  u += 0x7fffu + ((u >> 16) & 1u);
  return (unsigned short)(u >> 16);
}
__device__ __forceinline__ float bf2f(unsigned short h) {
  return __uint_as_float(((unsigned int)h) << 16);
}
__device__ __forceinline__ float lrelu(float a) { return a >= 0.f ? a : 0.2f * a; }

// ---------------- zero workspace region ----------------
__global__ void zero_kernel(int* __restrict__ p, int n) {
  int i = blockIdx.x * blockDim.x + threadIdx.x;
  int stride = gridDim.x * blockDim.x;
  for (; i < n; i += stride) p[i] = 0;
}

// ---------------- GEMM: xl[n,c] = sum_k x[n,k] * W[c,k]  (f32 in, bf16 out) ----------------
__global__ __launch_bounds__(256) void gemm_kernel(
    const float* __restrict__ x, const float* __restrict__ w,
    unsigned short* __restrict__ xl, int n) {
  __shared__ __align__(16) unsigned short xs[64 * 128];   // 16 KB, swizzled
  __shared__ __align__(16) unsigned short wl[128 * 128];  // 32 KB, swizzled
  const int t = threadIdx.x;
  const int r0 = blockIdx.x * 64;
  // stage W (128x128 f32 -> bf16)
#pragma unroll
  for (int i = 0; i < 16; ++i) {
    int f4 = t + i * 256;
    int row = f4 >> 5;
    int kk = (f4 & 31) << 2;
    float4 v = *(const float4*)(w + row * 128 + kk);
    ushort4 b;
    b.x = f2bf(v.x); b.y = f2bf(v.y); b.z = f2bf(v.z); b.w = f2bf(v.w);
    int boff = (kk << 1) ^ ((row & 7) << 4);
    *(ushort4*)((char*)wl + row * 256 + boff) = b;
  }
  // stage x tile (64 rows)
#pragma unroll
  for (int i = 0; i < 8; ++i) {
    int f4 = t + i * 256;
    int row = f4 >> 5;
    int kk = (f4 & 31) << 2;
    int gr = r0 + row;
    float4 v;
    if (gr < n) v = *(const float4*)(x + gr * 128 + kk);
    else { v.x = 0.f; v.y = 0.f; v.z = 0.f; v.w = 0.f; }
    ushort4 b;
    b.x = f2bf(v.x); b.y = f2bf(v.y); b.z = f2bf(v.z); b.w = f2bf(v.w);
    int boff = (kk << 1) ^ ((row & 7) << 4);
    *(ushort4*)((char*)xs + row * 256 + boff) = b;
  }
  __syncthreads();
  const int wid = t >> 6, lane = t & 63;
  const int m16 = lane & 15, kg = lane >> 4;
  const int arow = wid * 16 + m16;
  const f32x4 vzero = {0.f, 0.f, 0.f, 0.f};
  f32x4 acc[8];
#pragma unroll
  for (int i = 0; i < 8; ++i) acc[i] = vzero;
#pragma unroll
  for (int s = 0; s < 4; ++s) {
    int kb = s * 64 + kg * 16;
    bf16x8 a = *(const bf16x8*)((const char*)xs + arow * 256 + (kb ^ ((arow & 7) << 4)));
#pragma unroll
    for (int cf = 0; cf < 8; ++cf) {
      int wrow = cf * 16 + m16;
      bf16x8 b = *(const bf16x8*)((const char*)wl + wrow * 256 + (kb ^ ((wrow & 7) << 4)));
      acc[cf] = __builtin_amdgcn_mfma_f32_16x16x32_bf16(a, b, acc[cf], 0, 0, 0);
    }
  }
  // C/D layout: col = cf*16 + (lane&15), row = wid*16 + (lane>>4)*4 + q
  const int crow0 = wid * 16 + (lane >> 4) * 4;
#pragma unroll
  for (int q = 0; q < 4; ++q) {
    int gr = r0 + crow0 + q;
    if (gr < n) {
#pragma unroll
      for (int cf = 0; cf < 8; ++cf)
        xl[gr * 128 + cf * 16 + m16] = f2bf(acc[cf][q]);
    }
  }
}

// ---------------- per-node attention scalars ai / aj ----------------
__global__ __launch_bounds__(256) void atts_kernel(
    const unsigned short* __restrict__ xl, const float* __restrict__ emb,
    const float* __restrict__ att_i, const float* __restrict__ att_j,
    const float* __restrict__ att_em_i, const float* __restrict__ att_em_j,
    float* __restrict__ ai, float* __restrict__ aj, int n) {
  int wid = threadIdx.x >> 6, lane = threadIdx.x & 63;
  int node = blockIdx.x * 4 + wid;
  if (node >= n) return;
  int c0 = lane, c1 = lane + 64;
  float x0 = bf2f(xl[node * 128 + c0]);
  float x1 = bf2f(xl[node * 128 + c1]);
  float e0 = emb[node * 128 + c0];
  float e1 = emb[node * 128 + c1];
  float si = x0 * att_i[c0] + x1 * att_i[c1] + e0 * att_em_i[c0] + e1 * att_em_i[c1];
  float sj = x0 * att_j[c0] + x1 * att_j[c1] + e0 * att_em_j[c0] + e1 * att_em_j[c1];
#pragma unroll
  for (int off = 32; off > 0; off >>= 1) {
    si += __shfl_xor(si, off);
    sj += __shfl_xor(sj, off);
  }
  if (lane == 0) { ai[node] = si; aj[node] = sj; }
}

// ---------------- CSR build ----------------
__global__ void count_kernel(const int* __restrict__ dst, int* __restrict__ cnt, int E) {
  int e = blockIdx.x * blockDim.x + threadIdx.x;
  if (e < E) atomicAdd(&cnt[dst[e]], 1);
}

// multi-block scan, step 1: per-block exclusive scan + block sums
__global__ __launch_bounds__(1024) void scan1_kernel(
    const int* __restrict__ cnt, int* __restrict__ rp, int* __restrict__ bsum, int n) {
  __shared__ int wsum[16];
  int t = threadIdx.x, lane = t & 63, wid = t >> 6;
  int i = blockIdx.x * 1024 + t;
  int v = (i < n) ? cnt[i] : 0;
  int incl = v;
#pragma unroll
  for (int off = 1; off < 64; off <<= 1) {
    int u = __shfl_up(incl, off);
    if (lane >= off) incl += u;
  }
  if (lane == 63) wsum[wid] = incl;
  __syncthreads();
  if (t < 16) {
    int wv = wsum[t];
    int winc = wv;
#pragma unroll
    for (int off = 1; off < 16; off <<= 1) {
      int u = __shfl_up(winc, off);
      if (t >= off) winc += u;
    }
    wsum[t] = winc - wv;  // exclusive wave offset
  }
  __syncthreads();
  int excl = wsum[wid] + incl - v;
  if (i < n) rp[i] = excl;
  if (t == 1023) bsum[blockIdx.x] = excl + v;
}

// step 2: scan block sums (single 64-lane block), write total to rp[n]
__global__ __launch_bounds__(64) void scan2_kernel(
    int* __restrict__ bsum, int* __restrict__ rp, int nb, int n) {
  int t = threadIdx.x;
  int carry = 0;
  for (int base = 0; base < nb; base += 64) {
    int idx = base + t;
    int v = (idx < nb) ? bsum[idx] : 0;
    int incl = v;
#pragma unroll
    for (int off = 1; off < 64; off <<= 1) {
      int u = __shfl_up(incl, off);
      if (t >= off) incl += u;
    }
    if (idx < nb) bsum[idx] = carry + incl - v;
    carry += __shfl(incl, 63);
  }
  if (t == 0) rp[n] = carry;
}

// step 3: add block offsets
__global__ __launch_bounds__(256) void scan3_kernel(
    const int* __restrict__ bsum, int* __restrict__ rp, int n) {
  int i = blockIdx.x * blockDim.x + threadIdx.x;
  if (i < n) rp[i] += bsum[i >> 10];
}

__global__ void scatter_kernel(const int* __restrict__ src, const int* __restrict__ dst,
                               const int* __restrict__ rp, int* __restrict__ fill,
                               int* __restrict__ csr, int E) {
  int e = blockIdx.x * blockDim.x + threadIdx.x;
  if (e < E) {
    int d = dst[e];
    int pos = rp[d] + atomicAdd(&fill[d], 1);
    csr[pos] = src[e];
  }
}

// ---------------- fused segment-softmax + aggregation: one wave per node ----------------
// Online softmax per 64-edge chunk: exp/lrelu/aj-gather are lane-parallel,
// (we, idx) staged in wave-private LDS, feature gather unrolled x4 for MLP.
__global__ __launch_bounds__(256) void agg_kernel(
    const float* __restrict__ ai, const float* __restrict__ aj,
    const unsigned short* __restrict__ xl,
    const int* __restrict__ row_ptr, const int* __restrict__ csr_src,
    const float* __restrict__ bias, float* __restrict__ out, int n) {
  __shared__ float s_we[4][64];
  __shared__ int s_id[4][64];
  int wid = threadIdx.x >> 6, lane = threadIdx.x & 63;
  int node = blockIdx.x * 4 + wid;
  if (node >= n) return;
  int beg = row_ptr[node], end = row_ptr[node + 1];
  float ain = ai[node];
  float a_self = lrelu(ain + aj[node]);
  float m = a_self;          // running max (>= a_self always)
  float dl = 0.f;            // per-lane denom partial, scaled to current m
  float acc0 = 0.f, acc1 = 0.f;
  const int c0 = lane * 2;
  for (int cs = beg; cs < end; cs += 64) {
    int ce = min(64, end - cs);
    int s = 0;
    float a = -3.4e38f;
    if (lane < ce) {
      s = csr_src[cs + lane];
      a = lrelu(ain + aj[s]);
    }
    float cm = a;
#pragma unroll
    for (int off = 32; off > 0; off >>= 1) cm = fmaxf(cm, __shfl_xor(cm, off));
    float nm = fmaxf(m, cm);
    float scale = __expf(m - nm);
    dl *= scale; acc0 *= scale; acc1 *= scale;
    m = nm;
    float we = (lane < ce) ? __expf(a - nm) : 0.f;
    dl += we;
    s_we[wid][lane] = we;
    s_id[wid][lane] = s;
    // wave-private LDS: same wave produces and consumes, no barrier needed
    int j = 0;
    for (; j + 4 <= ce; j += 4) {
      float w0 = s_we[wid][j],     w1 = s_we[wid][j + 1];
      float w2 = s_we[wid][j + 2], w3 = s_we[wid][j + 3];
      int i0 = s_id[wid][j],     i1 = s_id[wid][j + 1];
      int i2 = s_id[wid][j + 2], i3 = s_id[wid][j + 3];
      ushort2 v0 = *(const ushort2*)(xl + i0 * 128 + c0);
      ushort2 v1 = *(const ushort2*)(xl + i1 * 128 + c0);
      ushort2 v2 = *(const ushort2*)(xl + i2 * 128 + c0);
      ushort2 v3 = *(const ushort2*)(xl + i3 * 128 + c0);
      acc0 += w0 * bf2f(v0.x); acc1 += w0 * bf2f(v0.y);
      acc0 += w1 * bf2f(v1.x); acc1 += w1 * bf2f(v1.y);
      acc0 += w2 * bf2f(v2.x); acc1 += w2 * bf2f(v2.y);
      acc0 += w3 * bf2f(v3.x); acc1 += w3 * bf2f(v3.y);
    }
    for (; j < ce; ++j) {
      float w0 = s_we[wid][j];
      int i0 = s_id[wid][j];
      ushort2 v0 = *(const ushort2*)(xl + i0 * 128 + c0);
      acc0 += w0 * bf2f(v0.x); acc1 += w0 * bf2f(v0.y);
    }
  }
  float w_self = __expf(a_self - m);
#pragma unroll
  for (int off = 32; off > 0; off >>= 1) dl += __shfl_xor(dl, off);
  float inv = 1.f / (dl + w_self + 1e-16f);
  ushort2 u = *(const ushort2*)(xl + node * 128 + c0);
  float2 o;
  o.x = (acc0 + w_self * bf2f(u.x)) * inv + bias[c0];
  o.y = (acc1 + w_self * bf2f(u.y)) * inv + bias[c0 + 1];
  *(float2*)(out + node * 128 + c0) = o;
}

// ---------------- BatchNorm stats + apply ----------------
__global__ __launch_bounds__(256) void bnstat_kernel(
    const float* __restrict__ out, float* __restrict__ sums,
    float* __restrict__ sumsq, int n) {
  int c = threadIdx.x & 127;
  int half = threadIdx.x >> 7;
  float s = 0.f, q = 0.f;
  for (int r = blockIdx.x * 2 + half; r < n; r += gridDim.x * 2) {
    float v = out[r * 128 + c];
    s += v;
    q += v * v;
  }
  atomicAdd(&sums[c], s);
  atomicAdd(&sumsq[c], q);
}

__global__ __launch_bounds__(256) void bnapply_kernel(
    float* __restrict__ out, const float* __restrict__ sums,
    const float* __restrict__ sumsq, const float* __restrict__ gamma,
    const float* __restrict__ beta, int n, float invN) {
  int total = n * 128;
  int i = blockIdx.x * blockDim.x + threadIdx.x;
  int stride = gridDim.x * blockDim.x;
  for (; i < total; i += stride) {
    int c = i & 127;
    float mu = sums[c] * invN;
    float var = sumsq[c] * invN - mu * mu;
    out[i] = (out[i] - mu) * rsqrtf(var + 1e-5f) * gamma[c] + beta[c];
  }
}

extern "C" void kernel_launch(void* const* d_in, const int* in_sizes, int n_in,
                              void* d_out, int out_size, void* d_ws, size_t ws_size,
                              hipStream_t stream) {
  (void)n_in; (void)out_size; (void)ws_size;
  const float* x = (const float*)d_in[0];
  const int* ei = (const int*)d_in[1];
  const float* emb = (const float*)d_in[2];
  const float* lin_w = (const float*)d_in[3];
  const float* att_i = (const float*)d_in[4];
  const float* att_j = (const float*)d_in[5];
  const float* att_em_i = (const float*)d_in[6];
  const float* att_em_j = (const float*)d_in[7];
  const float* bias = (const float*)d_in[8];
  const float* gamma = (const float*)d_in[9];
  const float* beta = (const float*)d_in[10];
  float* out = (float*)d_out;
  const int N = in_sizes[0] / 128;
  const int E = in_sizes[1] / 2;
  const int* src = ei;
  const int* dst = ei + E;
  const int NB = (N + 1023) / 1024;

  auto align_up = [](size_t v) { return (v + 255) & ~(size_t)255; };
  size_t off = 0;
  size_t xl_off = off;    off = align_up(off + (size_t)N * 128 * 2);
  size_t ai_off = off;    off = align_up(off + (size_t)N * 4);
  size_t aj_off = off;    off = align_up(off + (size_t)N * 4);
  size_t rp_off = off;    off = align_up(off + (size_t)(N + 1) * 4);
  size_t csr_off = off;   off = align_up(off + (size_t)E * 4);
  size_t cnt_off = off;   off = align_up(off + (size_t)N * 4);
  size_t fill_off = off;  off = align_up(off + (size_t)N * 4);
  size_t sums_off = off;  off = align_up(off + 512);
  size_t sumsq_off = off; off = align_up(off + 512);
  size_t bsum_off = off;  off = align_up(off + (size_t)(NB + 1) * 4);
  size_t end_off = off;

  char* ws = (char*)d_ws;
  unsigned short* xl = (unsigned short*)(ws + xl_off);
  float* ai = (float*)(ws + ai_off);
  float* aj = (float*)(ws + aj_off);
  int* rp = (int*)(ws + rp_off);
  int* csr = (int*)(ws + csr_off);
  int* cnt = (int*)(ws + cnt_off);
  int* fill = (int*)(ws + fill_off);
  float* sums = (float*)(ws + sums_off);
  float* sumsq = (float*)(ws + sumsq_off);
  int* bsum = (int*)(ws + bsum_off);

  // zero cnt/fill/sums/sumsq/bsum (contiguous region)
  int zwords = (int)((end_off - cnt_off) / 4);
  hipLaunchKernelGGL(zero_kernel, dim3((zwords + 255) / 256), dim3(256), 0, stream,
                     cnt, zwords);
  hipLaunchKernelGGL(gemm_kernel, dim3((N + 63) / 64), dim3(256), 0, stream,
                     x, lin_w, xl, N);
  hipLaunchKernelGGL(atts_kernel, dim3((N + 3) / 4), dim3(256), 0, stream,
                     xl, emb, att_i, att_j, att_em_i, att_em_j, ai, aj, N);
  hipLaunchKernelGGL(count_kernel, dim3((E + 255) / 256), dim3(256), 0, stream,
                     dst, cnt, E);
  hipLaunchKernelGGL(scan1_kernel, dim3(NB), dim3(1024), 0, stream, cnt, rp, bsum, N);
  hipLaunchKernelGGL(scan2_kernel, dim3(1), dim3(64), 0, stream, bsum, rp, NB, N);
  hipLaunchKernelGGL(scan3_kernel, dim3((N + 255) / 256), dim3(256), 0, stream,
                     bsum, rp, N);
  hipLaunchKernelGGL(scatter_kernel, dim3((E + 255) / 256), dim3(256), 0, stream,
                     src, dst, rp, fill, csr, E);
  hipLaunchKernelGGL(agg_kernel, dim3((N + 3) / 4), dim3(256), 0, stream,
                     ai, aj, xl, rp, csr, bias, out, N);
  hipLaunchKernelGGL(bnstat_kernel, dim3(256), dim3(256), 0, stream,
                     out, sums, sumsq, N);
  hipLaunchKernelGGL(bnapply_kernel, dim3(2048), dim3(256), 0, stream,
                     out, sums, sumsq, gamma, beta, N, 1.0f / (float)N);
}

// Round 5
// 262.778 us; speedup vs baseline: 1.4763x; 1.1072x over previous
//
#include <hip/hip_runtime.h>

typedef short bf16x8 __attribute__((ext_vector_type(8)));
typedef float f32x4 __attribute__((ext_vector_type(4)));

__device__ __forceinline__ unsigned short f2bf(float f) {
  unsigned int u = __float_as_uint(f);
  u += 0x7fffu + ((u >> 16) & 1u);
  return (unsigned short)(u >> 16);
}
__device__ __forceinline__ float bf2f(unsigned short h) {
  return __uint_as_float(((unsigned int)h) << 16);
}
__device__ __forceinline__ float lrelu(float a) { return a >= 0.f ? a : 0.2f * a; }

// ---------------- zero workspace region ----------------
__global__ void zero_kernel(int* __restrict__ p, int n) {
  int i = blockIdx.x * blockDim.x + threadIdx.x;
  int stride = gridDim.x * blockDim.x;
  for (; i < n; i += stride) p[i] = 0;
}

// ---------------- GEMM: xl[n,c] = sum_k x[n,k] * W[c,k]  (f32 in, bf16 out) ----------------
__global__ __launch_bounds__(256) void gemm_kernel(
    const float* __restrict__ x, const float* __restrict__ w,
    unsigned short* __restrict__ xl, int n) {
  __shared__ __align__(16) unsigned short xs[64 * 128];   // 16 KB, swizzled
  __shared__ __align__(16) unsigned short wl[128 * 128];  // 32 KB, swizzled
  const int t = threadIdx.x;
  const int r0 = blockIdx.x * 64;
  // stage W (128x128 f32 -> bf16)
#pragma unroll
  for (int i = 0; i < 16; ++i) {
    int f4 = t + i * 256;
    int row = f4 >> 5;
    int kk = (f4 & 31) << 2;
    float4 v = *(const float4*)(w + row * 128 + kk);
    ushort4 b;
    b.x = f2bf(v.x); b.y = f2bf(v.y); b.z = f2bf(v.z); b.w = f2bf(v.w);
    int boff = (kk << 1) ^ ((row & 7) << 4);
    *(ushort4*)((char*)wl + row * 256 + boff) = b;
  }
  // stage x tile (64 rows)
#pragma unroll
  for (int i = 0; i < 8; ++i) {
    int f4 = t + i * 256;
    int row = f4 >> 5;
    int kk = (f4 & 31) << 2;
    int gr = r0 + row;
    float4 v;
    if (gr < n) v = *(const float4*)(x + gr * 128 + kk);
    else { v.x = 0.f; v.y = 0.f; v.z = 0.f; v.w = 0.f; }
    ushort4 b;
    b.x = f2bf(v.x); b.y = f2bf(v.y); b.z = f2bf(v.z); b.w = f2bf(v.w);
    int boff = (kk << 1) ^ ((row & 7) << 4);
    *(ushort4*)((char*)xs + row * 256 + boff) = b;
  }
  __syncthreads();
  const int wid = t >> 6, lane = t & 63;
  const int m16 = lane & 15, kg = lane >> 4;
  const int arow = wid * 16 + m16;
  const f32x4 vzero = {0.f, 0.f, 0.f, 0.f};
  f32x4 acc[8];
#pragma unroll
  for (int i = 0; i < 8; ++i) acc[i] = vzero;
#pragma unroll
  for (int s = 0; s < 4; ++s) {
    int kb = s * 64 + kg * 16;
    bf16x8 a = *(const bf16x8*)((const char*)xs + arow * 256 + (kb ^ ((arow & 7) << 4)));
#pragma unroll
    for (int cf = 0; cf < 8; ++cf) {
      int wrow = cf * 16 + m16;
      bf16x8 b = *(const bf16x8*)((const char*)wl + wrow * 256 + (kb ^ ((wrow & 7) << 4)));
      acc[cf] = __builtin_amdgcn_mfma_f32_16x16x32_bf16(a, b, acc[cf], 0, 0, 0);
    }
  }
  // C/D layout: col = cf*16 + (lane&15), row = wid*16 + (lane>>4)*4 + q
  const int crow0 = wid * 16 + (lane >> 4) * 4;
#pragma unroll
  for (int q = 0; q < 4; ++q) {
    int gr = r0 + crow0 + q;
    if (gr < n) {
#pragma unroll
      for (int cf = 0; cf < 8; ++cf)
        xl[gr * 128 + cf * 16 + m16] = f2bf(acc[cf][q]);
    }
  }
}

// ---------------- per-node attention scalars ai / aj ----------------
__global__ __launch_bounds__(256) void atts_kernel(
    const unsigned short* __restrict__ xl, const float* __restrict__ emb,
    const float* __restrict__ att_i, const float* __restrict__ att_j,
    const float* __restrict__ att_em_i, const float* __restrict__ att_em_j,
    float* __restrict__ ai, float* __restrict__ aj, int n) {
  int wid = threadIdx.x >> 6, lane = threadIdx.x & 63;
  int node = blockIdx.x * 4 + wid;
  if (node >= n) return;
  int c0 = lane, c1 = lane + 64;
  float x0 = bf2f(xl[node * 128 + c0]);
  float x1 = bf2f(xl[node * 128 + c1]);
  float e0 = emb[node * 128 + c0];
  float e1 = emb[node * 128 + c1];
  float si = x0 * att_i[c0] + x1 * att_i[c1] + e0 * att_em_i[c0] + e1 * att_em_i[c1];
  float sj = x0 * att_j[c0] + x1 * att_j[c1] + e0 * att_em_j[c0] + e1 * att_em_j[c1];
#pragma unroll
  for (int off = 32; off > 0; off >>= 1) {
    si += __shfl_xor(si, off);
    sj += __shfl_xor(sj, off);
  }
  if (lane == 0) { ai[node] = si; aj[node] = sj; }
}

// ---------------- CSR build ----------------
// count + per-edge rank in ONE atomic pass; 4 edges/thread for MLP
__global__ __launch_bounds__(256) void count_rank_kernel(
    const int* __restrict__ dst, int* __restrict__ cnt, int* __restrict__ pw, int E) {
  int e = (blockIdx.x * blockDim.x + threadIdx.x) * 4;
  if (e + 3 < E) {
    int4 d4 = *(const int4*)(dst + e);
    int4 p4;
    p4.x = atomicAdd(&cnt[d4.x], 1);
    p4.y = atomicAdd(&cnt[d4.y], 1);
    p4.z = atomicAdd(&cnt[d4.z], 1);
    p4.w = atomicAdd(&cnt[d4.w], 1);
    *(int4*)(pw + e) = p4;
  } else {
    for (; e < E; ++e) pw[e] = atomicAdd(&cnt[dst[e]], 1);
  }
}

// multi-block scan, step 1: per-block exclusive scan + block sums
__global__ __launch_bounds__(1024) void scan1_kernel(
    const int* __restrict__ cnt, int* __restrict__ rp, int* __restrict__ bsum, int n) {
  __shared__ int wsum[16];
  int t = threadIdx.x, lane = t & 63, wid = t >> 6;
  int i = blockIdx.x * 1024 + t;
  int v = (i < n) ? cnt[i] : 0;
  int incl = v;
#pragma unroll
  for (int off = 1; off < 64; off <<= 1) {
    int u = __shfl_up(incl, off);
    if (lane >= off) incl += u;
  }
  if (lane == 63) wsum[wid] = incl;
  __syncthreads();
  if (t < 16) {
    int wv = wsum[t];
    int winc = wv;
#pragma unroll
    for (int off = 1; off < 16; off <<= 1) {
      int u = __shfl_up(winc, off);
      if (t >= off) winc += u;
    }
    wsum[t] = winc - wv;  // exclusive wave offset
  }
  __syncthreads();
  int excl = wsum[wid] + incl - v;
  if (i < n) rp[i] = excl;
  if (t == 1023) bsum[blockIdx.x] = excl + v;
}

// step 2: scan block sums (single 64-lane block), write total to rp[n]
__global__ __launch_bounds__(64) void scan2_kernel(
    int* __restrict__ bsum, int* __restrict__ rp, int nb, int n) {
  int t = threadIdx.x;
  int carry = 0;
  for (int base = 0; base < nb; base += 64) {
    int idx = base + t;
    int v = (idx < nb) ? bsum[idx] : 0;
    int incl = v;
#pragma unroll
    for (int off = 1; off < 64; off <<= 1) {
      int u = __shfl_up(incl, off);
      if (t >= off) incl += u;
    }
    if (idx < nb) bsum[idx] = carry + incl - v;
    carry += __shfl(incl, 63);
  }
  if (t == 0) rp[n] = carry;
}

// step 3: add block offsets
__global__ __launch_bounds__(256) void scan3_kernel(
    const int* __restrict__ bsum, int* __restrict__ rp, int n) {
  int i = blockIdx.x * blockDim.x + threadIdx.x;
  if (i < n) rp[i] += bsum[i >> 10];
}

// atomic-free scatter: pos = rp[dst] + precomputed rank; 4 edges/thread
__global__ __launch_bounds__(256) void scatter_kernel(
    const int* __restrict__ src, const int* __restrict__ dst,
    const int* __restrict__ rp, const int* __restrict__ pw,
    int* __restrict__ csr, int E) {
  int e = (blockIdx.x * blockDim.x + threadIdx.x) * 4;
  if (e + 3 < E) {
    int4 s4 = *(const int4*)(src + e);
    int4 d4 = *(const int4*)(dst + e);
    int4 p4 = *(const int4*)(pw + e);
    int r0 = rp[d4.x], r1 = rp[d4.y], r2 = rp[d4.z], r3 = rp[d4.w];
    csr[r0 + p4.x] = s4.x;
    csr[r1 + p4.y] = s4.y;
    csr[r2 + p4.z] = s4.z;
    csr[r3 + p4.w] = s4.w;
  } else {
    for (; e < E; ++e) csr[rp[dst[e]] + pw[e]] = src[e];
  }
}

// ---------------- fused segment-softmax + aggregation: one wave per node ----------------
// Online softmax per 64-edge chunk: exp/lrelu/aj-gather are lane-parallel,
// (we, idx) staged in wave-private LDS, feature gather unrolled x4 for MLP.
__global__ __launch_bounds__(256) void agg_kernel(
    const float* __restrict__ ai, const float* __restrict__ aj,
    const unsigned short* __restrict__ xl,
    const int* __restrict__ row_ptr, const int* __restrict__ csr_src,
    const float* __restrict__ bias, float* __restrict__ out, int n) {
  __shared__ float s_we[4][64];
  __shared__ int s_id[4][64];
  int wid = threadIdx.x >> 6, lane = threadIdx.x & 63;
  int node = blockIdx.x * 4 + wid;
  if (node >= n) return;
  int beg = row_ptr[node], end = row_ptr[node + 1];
  float ain = ai[node];
  float a_self = lrelu(ain + aj[node]);
  float m = a_self;          // running max (>= a_self always)
  float dl = 0.f;            // per-lane denom partial, scaled to current m
  float acc0 = 0.f, acc1 = 0.f;
  const int c0 = lane * 2;
  for (int cs = beg; cs < end; cs += 64) {
    int ce = min(64, end - cs);
    int s = 0;
    float a = -3.4e38f;
    if (lane < ce) {
      s = csr_src[cs + lane];
      a = lrelu(ain + aj[s]);
    }
    float cm = a;
#pragma unroll
    for (int off = 32; off > 0; off >>= 1) cm = fmaxf(cm, __shfl_xor(cm, off));
    float nm = fmaxf(m, cm);
    float scale = __expf(m - nm);
    dl *= scale; acc0 *= scale; acc1 *= scale;
    m = nm;
    float we = (lane < ce) ? __expf(a - nm) : 0.f;
    dl += we;
    s_we[wid][lane] = we;
    s_id[wid][lane] = s;
    // wave-private LDS: same wave produces and consumes, no barrier needed
    int j = 0;
    for (; j + 4 <= ce; j += 4) {
      float w0 = s_we[wid][j],     w1 = s_we[wid][j + 1];
      float w2 = s_we[wid][j + 2], w3 = s_we[wid][j + 3];
      int i0 = s_id[wid][j],     i1 = s_id[wid][j + 1];
      int i2 = s_id[wid][j + 2], i3 = s_id[wid][j + 3];
      ushort2 v0 = *(const ushort2*)(xl + i0 * 128 + c0);
      ushort2 v1 = *(const ushort2*)(xl + i1 * 128 + c0);
      ushort2 v2 = *(const ushort2*)(xl + i2 * 128 + c0);
      ushort2 v3 = *(const ushort2*)(xl + i3 * 128 + c0);
      acc0 += w0 * bf2f(v0.x); acc1 += w0 * bf2f(v0.y);
      acc0 += w1 * bf2f(v1.x); acc1 += w1 * bf2f(v1.y);
      acc0 += w2 * bf2f(v2.x); acc1 += w2 * bf2f(v2.y);
      acc0 += w3 * bf2f(v3.x); acc1 += w3 * bf2f(v3.y);
    }
    for (; j < ce; ++j) {
      float w0 = s_we[wid][j];
      int i0 = s_id[wid][j];
      ushort2 v0 = *(const ushort2*)(xl + i0 * 128 + c0);
      acc0 += w0 * bf2f(v0.x); acc1 += w0 * bf2f(v0.y);
    }
  }
  float w_self = __expf(a_self - m);
#pragma unroll
  for (int off = 32; off > 0; off >>= 1) dl += __shfl_xor(dl, off);
  float inv = 1.f / (dl + w_self + 1e-16f);
  ushort2 u = *(const ushort2*)(xl + node * 128 + c0);
  float2 o;
  o.x = (acc0 + w_self * bf2f(u.x)) * inv + bias[c0];
  o.y = (acc1 + w_self * bf2f(u.y)) * inv + bias[c0 + 1];
  *(float2*)(out + node * 128 + c0) = o;
}

// ---------------- BatchNorm stats + apply ----------------
__global__ __launch_bounds__(256) void bnstat_kernel(
    const float* __restrict__ out, float* __restrict__ sums,
    float* __restrict__ sumsq, int n) {
  int c = threadIdx.x & 127;
  int half = threadIdx.x >> 7;
  float s = 0.f, q = 0.f;
  for (int r = blockIdx.x * 2 + half; r < n; r += gridDim.x * 2) {
    float v = out[r * 128 + c];
    s += v;
    q += v * v;
  }
  atomicAdd(&sums[c], s);
  atomicAdd(&sumsq[c], q);
}

__global__ __launch_bounds__(256) void bnapply_kernel(
    float* __restrict__ out, const float* __restrict__ sums,
    const float* __restrict__ sumsq, const float* __restrict__ gamma,
    const float* __restrict__ beta, int n, float invN) {
  int total = n * 128;
  int i = blockIdx.x * blockDim.x + threadIdx.x;
  int stride = gridDim.x * blockDim.x;
  for (; i < total; i += stride) {
    int c = i & 127;
    float mu = sums[c] * invN;
    float var = sumsq[c] * invN - mu * mu;
    out[i] = (out[i] - mu) * rsqrtf(var + 1e-5f) * gamma[c] + beta[c];
  }
}

extern "C" void kernel_launch(void* const* d_in, const int* in_sizes, int n_in,
                              void* d_out, int out_size, void* d_ws, size_t ws_size,
                              hipStream_t stream) {
  (void)n_in; (void)out_size; (void)ws_size;
  const float* x = (const float*)d_in[0];
  const int* ei = (const int*)d_in[1];
  const float* emb = (const float*)d_in[2];
  const float* lin_w = (const float*)d_in[3];
  const float* att_i = (const float*)d_in[4];
  const float* att_j = (const float*)d_in[5];
  const float* att_em_i = (const float*)d_in[6];
  const float* att_em_j = (const float*)d_in[7];
  const float* bias = (const float*)d_in[8];
  const float* gamma = (const float*)d_in[9];
  const float* beta = (const float*)d_in[10];
  float* out = (float*)d_out;
  const int N = in_sizes[0] / 128;
  const int E = in_sizes[1] / 2;
  const int* src = ei;
  const int* dst = ei + E;
  const int NB = (N + 1023) / 1024;

  auto align_up = [](size_t v) { return (v + 255) & ~(size_t)255; };
  size_t off = 0;
  size_t xl_off = off;    off = align_up(off + (size_t)N * 128 * 2);
  size_t ai_off = off;    off = align_up(off + (size_t)N * 4);
  size_t aj_off = off;    off = align_up(off + (size_t)N * 4);
  size_t rp_off = off;    off = align_up(off + (size_t)(N + 1) * 4);
  size_t csr_off = off;   off = align_up(off + (size_t)E * 4);
  size_t pw_off = off;    off = align_up(off + (size_t)E * 4);
  size_t bsum_off = off;  off = align_up(off + (size_t)(NB + 1) * 4);
  size_t cnt_off = off;   off = align_up(off + (size_t)N * 4);
  size_t sums_off = off;  off = align_up(off + 512);
  size_t sumsq_off = off; off = align_up(off + 512);
  size_t end_off = off;

  char* ws = (char*)d_ws;
  unsigned short* xl = (unsigned short*)(ws + xl_off);
  float* ai = (float*)(ws + ai_off);
  float* aj = (float*)(ws + aj_off);
  int* rp = (int*)(ws + rp_off);
  int* csr = (int*)(ws + csr_off);
  int* pw = (int*)(ws + pw_off);
  int* bsum = (int*)(ws + bsum_off);
  int* cnt = (int*)(ws + cnt_off);
  float* sums = (float*)(ws + sums_off);
  float* sumsq = (float*)(ws + sumsq_off);

  // zero cnt/sums/sumsq (contiguous region at the end)
  int zwords = (int)((end_off - cnt_off) / 4);
  hipLaunchKernelGGL(zero_kernel, dim3((zwords + 255) / 256), dim3(256), 0, stream,
                     cnt, zwords);
  hipLaunchKernelGGL(gemm_kernel, dim3((N + 63) / 64), dim3(256), 0, stream,
                     x, lin_w, xl, N);
  hipLaunchKernelGGL(atts_kernel, dim3((N + 3) / 4), dim3(256), 0, stream,
                     xl, emb, att_i, att_j, att_em_i, att_em_j, ai, aj, N);
  hipLaunchKernelGGL(count_rank_kernel, dim3((E / 4 + 255) / 256), dim3(256), 0, stream,
                     dst, cnt, pw, E);
  hipLaunchKernelGGL(scan1_kernel, dim3(NB), dim3(1024), 0, stream, cnt, rp, bsum, N);
  hipLaunchKernelGGL(scan2_kernel, dim3(1), dim3(64), 0, stream, bsum, rp, NB, N);
  hipLaunchKernelGGL(scan3_kernel, dim3((N + 255) / 256), dim3(256), 0, stream,
                     bsum, rp, N);
  hipLaunchKernelGGL(scatter_kernel, dim3((E / 4 + 255) / 256), dim3(256), 0, stream,
                     src, dst, rp, pw, csr, E);
  hipLaunchKernelGGL(agg_kernel, dim3((N + 3) / 4), dim3(256), 0, stream,
                     ai, aj, xl, rp, csr, bias, out, N);
  hipLaunchKernelGGL(bnstat_kernel, dim3(256), dim3(256), 0, stream,
                     out, sums, sumsq, N);
  hipLaunchKernelGGL(bnapply_kernel, dim3(2048), dim3(256), 0, stream,
                     out, sums, sumsq, gamma, beta, N, 1.0f / (float)N);
}